// Round 6
// baseline (41.975 us; speedup 1.0000x reference)
//
#include <hip/hip_runtime.h>
#include <hip/hip_bf16.h>

#define N_PED 1024
#define H 128
#define G 8
#define K_TOT 8192
#define HALF_NB 16.0f
#define INV_CELL 0.25f
#define LISTCAP 256      // max neighbors/ped (mean ~105, sd ~10 -> safe)
#define MLISTCAP 2048    // max matches/block (mean ~210 -> safe)

typedef __attribute__((ext_vector_type(8))) short bf16x8;
typedef __attribute__((ext_vector_type(4))) float f32x4;

__device__ __forceinline__ unsigned map_f2u(float v) {
    unsigned u = __float_as_uint(v);
    return (u & 0x80000000u) ? ~u : (u | 0x80000000u);
}
__device__ __forceinline__ float unmap_u2f(unsigned u) {
    return __uint_as_float((u & 0x80000000u) ? (u ^ 0x80000000u) : ~u);
}
__device__ __forceinline__ ushort f2bf(float f) {   // round-to-nearest-even
    unsigned u = __float_as_uint(f);
    return (ushort)((u + 0x7FFFu + ((u >> 16) & 1u)) >> 16);
}
__device__ __forceinline__ void gl_lds16(const void* g, void* l) {
    __builtin_amdgcn_global_load_lds(
        (const __attribute__((address_space(1))) void*)g,
        (__attribute__((address_space(3))) void*)l, 16, 0, 0);
}

// blocks 0..127   : W [8192][128] fp32 -> Wt [128][8192] bf16 (64-k slab each)
// blocks 128..159 : neighbor lists for 32 peds each: lists[p][e]=(j<<8)|cell
// blocks 160..161 : out[i][o] = b[o]  (bias seed for atomic epilogue)
__global__ __launch_bounds__(512) void prep(const float* __restrict__ hs,
                                            const float* __restrict__ pos,
                                            const float* __restrict__ W,
                                            const float* __restrict__ b,
                                            ushort* __restrict__ Wt,
                                            int* __restrict__ lists,
                                            int* __restrict__ cntg,
                                            float* __restrict__ out) {
    __shared__ __align__(16) char smem[33168];
    const int tid = threadIdx.x;
    const int bx  = blockIdx.x;

    if (bx < 128) {                               // ---- wconv ----
        float* tile = (float*)smem;               // [64][129]
        const int k0w = bx * 64;
        for (int x = tid; x < 64 * H; x += 512) {
            int r = x >> 7, c = x & 127;
            tile[r * 129 + c] = W[(size_t)(k0w + r) * H + c];
        }
        __syncthreads();
        const int col = tid >> 2;                 // 0..127
        const int kh  = (tid & 3) * 16;
        ushort tmp[16];
        #pragma unroll
        for (int t = 0; t < 16; ++t) tmp[t] = f2bf(tile[(kh + t) * 129 + col]);
        ushort* w0 = Wt + (size_t)col * K_TOT + k0w + kh;
        *(bf16x8*)w0       = *(const bf16x8*)&tmp[0];
        *(bf16x8*)(w0 + 8) = *(const bf16x8*)&tmp[8];
    } else if (bx < 160) {                        // ---- neighbor lists ----
        float2* pis   = (float2*)smem;            // 256 B
        int*    lcnt  = (int*)(smem + 256);       // 128 B
        int*    llist = (int*)(smem + 384);       // 32 KB
        const int base = (bx - 128) * 32;
        if (tid < 32) { pis[tid] = ((const float2*)pos)[base + tid]; lcnt[tid] = 0; }
        __syncthreads();
        for (int j = tid; j < N_PED; j += 512) {
            float2 pj = ((const float2*)pos)[j];
            #pragma unroll
            for (int p = 0; p < 32; ++p) {
                float rx = pj.x - pis[p].x;
                float ry = pj.y - pis[p].y;
                if (j != base + p && fabsf(rx) <= HALF_NB && fabsf(ry) <= HALF_NB) {
                    int gx = min(G - 1, max(0, (int)floorf((rx + HALF_NB) * INV_CELL)));
                    int gy = min(G - 1, max(0, (int)floorf((ry + HALF_NB) * INV_CELL)));
                    int slot = atomicAdd(&lcnt[p], 1);
                    if (slot < LISTCAP) llist[p * LISTCAP + slot] = (j << 8) | (gy * G + gx);
                }
            }
        }
        __syncthreads();
        for (int x = tid; x < 32 * 64; x += 512)   // bulk copy (garbage beyond cnt ok)
            ((int4*)lists)[base * 64 + x] = ((const int4*)llist)[x];
        if (tid < 32) cntg[base + tid] = min(lcnt[tid], LISTCAP);
    } else {                                      // ---- bias seed ----
        const float4* b4 = (const float4*)b;
        float4* out4 = (float4*)out;
        const int b0 = (bx - 160) * 16384;
        for (int i = tid; i < 16384; i += 512) {
            int g = b0 + i;
            out4[g] = b4[g & 31];
        }
    }
}

// grid (32, 16): block = 32 peds (m0) x cells 4cy..4cy+3 (K in [cy*512, cy*512+512)).
// Pools its own A-tile in LDS (no grid materialization), then MFMA GEMM with
// triple-buffered B staging, atomicAdd fp32 epilogue into bias-seeded out.
// LDS: A 32K | P 64K | B 48K (disjoint) -> first two B stages prefetch at entry,
// their latency hides under the entire pooling phase (T14 issue-early).
__global__ __launch_bounds__(512) void gemm_fused(const float* __restrict__ hs,
                                                  const ushort* __restrict__ Wt,
                                                  const int* __restrict__ lists,
                                                  const int* __restrict__ cntg,
                                                  float* __restrict__ out) {
    __shared__ __align__(16) char smem[147600];
    ushort* Alds  = (ushort*)smem;                // 32 KB [32][512] swizzled bf16
    int*    mlist = (int*)smem;                   // alias (dead before A3 writes)
    uint*   P     = (uint*)(smem + 32768);        // 64 KB [32][512] mapped-uint pool
    ushort* Blds  = (ushort*)(smem + 98304);      // 3 x 16 KB
    int*    mcnt  = (int*)(smem + 147456);
    int*    scnt  = (int*)(smem + 147460);        // 32 ints

    const int tid = threadIdx.x;
    const int m0  = blockIdx.x * 32;
    const int cy  = blockIdx.y;                   // cell group / K slice

    // B staging geometry (wave-level)
    const int wave = tid >> 6, lane = tid & 63;
    const int ll = lane & 15, lh = lane >> 4;
    const int lr8  = lane >> 3;
    const int cswz = (lane & 7) ^ (lr8 & 7);
    const ushort* B0 = Wt + (size_t)(16 * wave + lr8) * K_TOT + cy * 512 + cswz * 8;

#define STAGE(T, BUF)                                                         \
    do {                                                                      \
        gl_lds16(B0 + (T) * 64,             Blds + (BUF) * 8192 + (16 * wave) * 64);     \
        gl_lds16(B0 + (T) * 64 + 8 * K_TOT, Blds + (BUF) * 8192 + (16 * wave + 8) * 64); \
    } while (0)

    // issue stages 0,1 NOW -- latency hides under pooling (Blds disjoint from P)
    STAGE(0, 0);
    STAGE(1, 1);

    {   // init pool to map(0.0f) => empty cells -> 0 and clamp-at-0 for free
        uint4 iv = {0x80000000u, 0x80000000u, 0x80000000u, 0x80000000u};
        uint4* P4 = (uint4*)P;
        for (int i = tid; i < 4096; i += 512) P4[i] = iv;
        if (tid == 0) *mcnt = 0;
        if (tid < 32) scnt[tid] = cntg[m0 + tid];
    }
    __syncthreads();

    // A1: filter this block's cell-group matches into mlist
    for (int x = tid; x < 32 * 64; x += 512) {
        int p = x >> 6, q = x & 63;
        int4 v = ((const int4*)(lists + (size_t)(m0 + p) * LISTCAP))[q];
        int n = scnt[p];
        int e0 = q * 4;
        int vv[4] = {v.x, v.y, v.z, v.w};
        #pragma unroll
        for (int i = 0; i < 4; ++i) {
            if (e0 + i < n) {
                int pk = vv[i];
                int cell = pk & 255;
                if ((cell >> 2) == cy) {
                    int slot = atomicAdd(mcnt, 1);
                    if (slot < MLISTCAP)
                        mlist[slot] = ((pk >> 8) << 7) | (p << 2) | (cell & 3);
                }
            }
        }
    }
    __syncthreads();

    // A2: pool matches into P via LDS atomicMax (order-free, exact)
    const int mc = min(*mcnt, MLISTCAP);
    const float4* hs4 = (const float4*)hs;
    for (int u = tid; u < mc * 32; u += 512) {
        int m = u >> 5, f = u & 31;
        int pk = mlist[m];
        int j = pk >> 7, p = (pk >> 2) & 31, c = pk & 3;
        float4 v = hs4[j * 32 + f];
        uint* q = P + p * 512 + c * 128 + f * 4;
        atomicMax(q + 0, map_f2u(v.x));
        atomicMax(q + 1, map_f2u(v.y));
        atomicMax(q + 2, map_f2u(v.z));
        atomicMax(q + 3, map_f2u(v.w));
    }
    __syncthreads();

    // A3: convert P -> swizzled bf16 A-tile (mlist region now dead)
    for (int x = tid; x < 2048; x += 512) {
        int r = x >> 6, c = x & 63;
        const uint* src = P + r * 512 + c * 8;
        ushort tmp[8];
        #pragma unroll
        for (int i = 0; i < 8; ++i) tmp[i] = f2bf(unmap_u2f(src[i]));
        *(bf16x8*)&Alds[r * 512 + (c ^ (r & 7)) * 8] = *(const bf16x8*)tmp;
    }

    // GEMM: 8 waves, wave = (mt = w>>2) x (nq = w&3); per wave 16 rows x 32 cols
    const int mt = wave >> 2;
    const int nq = wave & 3;

    f32x4 acc[2] = {};

    // stage-0 loads are this wave's two oldest vmem ops; all pooling loads
    // were consumed in A2, so vmcnt(2) drains exactly stage 0.
    asm volatile("s_waitcnt vmcnt(2)" ::: "memory");
    __syncthreads();   // also covers A3 Alds visibility

    #pragma unroll
    for (int t = 0; t < 8; ++t) {
        if (t + 2 < 8) STAGE(t + 2, (t + 2) % 3);
        const ushort* Bb = Blds + (t % 3) * 8192;
        #pragma unroll
        for (int ks = 0; ks < 2; ++ks) {
            int ch  = ks * 4 + lh;       // chunk in BK (0..7)
            int gch = t * 8 + ch;        // global chunk (0..63) for A
            bf16x8 bfrag[2];
            #pragma unroll
            for (int nt = 0; nt < 2; ++nt) {
                int br = nq * 32 + nt * 16 + ll;
                bfrag[nt] = *(const bf16x8*)&Bb[br * 64 + ((ch ^ (br & 7)) * 8)];
            }
            int ar = mt * 16 + ll;
            bf16x8 afrag = *(const bf16x8*)&Alds[ar * 512 + ((gch ^ (ar & 7)) * 8)];
            acc[0] = __builtin_amdgcn_mfma_f32_16x16x32_bf16(afrag, bfrag[0], acc[0], 0, 0, 0);
            acc[1] = __builtin_amdgcn_mfma_f32_16x16x32_bf16(afrag, bfrag[1], acc[1], 0, 0, 0);
        }
        if (t + 1 < 8) {
            if (t + 2 < 8) asm volatile("s_waitcnt vmcnt(2)" ::: "memory");
            else           asm volatile("s_waitcnt vmcnt(0)" ::: "memory");
            __builtin_amdgcn_s_barrier();
        }
    }
#undef STAGE

    // epilogue: atomic fp32 partial-sum into bias-seeded out
    #pragma unroll
    for (int nt = 0; nt < 2; ++nt) {
        int col = nq * 32 + nt * 16 + ll;
        int row = m0 + mt * 16 + lh * 4;
        #pragma unroll
        for (int r = 0; r < 4; ++r)
            atomicAdd(&out[(size_t)(row + r) * H + col], acc[nt][r]);
    }
}

extern "C" void kernel_launch(void* const* d_in, const int* in_sizes, int n_in,
                              void* d_out, int out_size, void* d_ws, size_t ws_size,
                              hipStream_t stream) {
    const float* hs  = (const float*)d_in[0];   // [1024][128]
    const float* pos = (const float*)d_in[1];   // [1024][2]
    const float* Wm  = (const float*)d_in[2];   // [8192][128]
    const float* b   = (const float*)d_in[3];   // [128]
    float* out = (float*)d_out;                 // [1024][128]

    ushort* Wt    = (ushort*)d_ws;                              // 2 MB
    int*    lists = (int*)((char*)d_ws + (2u << 20));           // 1 MB
    int*    cntg  = (int*)((char*)d_ws + (3u << 20));           // 4 KB

    prep<<<162, 512, 0, stream>>>(hs, pos, Wm, b, Wt, lists, cntg, out);
    gemm_fused<<<dim3(32, 16), 512, 0, stream>>>(hs, Wt, lists, cntg, out);
}

// Round 7
// 40.646 us; speedup vs baseline: 1.0327x; 1.0327x over previous
//
#include <hip/hip_runtime.h>
#include <hip/hip_bf16.h>

#define N_PED 1024
#define H 128
#define G 8
#define NCELL 64
#define K_TOT 8192
#define HALF_NB 16.0f
#define INV_CELL 0.25f

#define KSPLIT 16
#define KC 512          // K per gemm block

typedef __attribute__((ext_vector_type(8))) short bf16x8;
typedef __attribute__((ext_vector_type(4))) float f32x4;

__device__ __forceinline__ unsigned map_f2u(float v) {
    unsigned u = __float_as_uint(v);
    return (u & 0x80000000u) ? ~u : (u | 0x80000000u);
}
__device__ __forceinline__ float unmap_u2f(unsigned u) {
    return __uint_as_float((u & 0x80000000u) ? (u ^ 0x80000000u) : ~u);
}
__device__ __forceinline__ ushort f2bf(float f) {   // round-to-nearest-even
    unsigned u = __float_as_uint(f);
    return (ushort)((u + 0x7FFFu + ((u >> 16) & 1u)) >> 16);
}

// blocks 0..1023  : build pooled grid row (bf16 [8192], PLAIN layout) for ped i
// blocks 1024..1151: convert+transpose 64-k slab of W into Wt bf16 [128][8192]
// blocks 1152..1153: out[i][o] = b[o]  (bias seed for atomic epilogue)
__global__ __launch_bounds__(512) void fused_pre(const float* __restrict__ hs,
                                                 const float* __restrict__ pos,
                                                 const float* __restrict__ W,
                                                 const float* __restrict__ b,
                                                 ushort* __restrict__ grid,
                                                 ushort* __restrict__ Wt,
                                                 float* __restrict__ out) {
    __shared__ __align__(16) char smem[36872];
    const int tid = threadIdx.x;

    if (blockIdx.x < N_PED) {
        unsigned* lgrid = (unsigned*)smem;            // 32768 B
        int*      list  = (int*)(smem + 32768);       // 4096 B
        int*      cnt   = (int*)(smem + 36864);       // 4 B
        const int i = blockIdx.x;

        const unsigned iu = 0x80000000u;              // map_f2u(0.0f)
        uint4 iv = {iu, iu, iu, iu};
        for (int k = tid; k < NCELL * H / 4; k += 512) ((uint4*)lgrid)[k] = iv;
        if (tid == 0) *cnt = 0;
        __syncthreads();

        const float2 pi = ((const float2*)pos)[i];
        for (int j = tid; j < N_PED; j += 512) {
            float2 pj = ((const float2*)pos)[j];
            float rx = pj.x - pi.x;
            float ry = pj.y - pi.y;
            if (j != i && fabsf(rx) <= HALF_NB && fabsf(ry) <= HALF_NB) {
                int gx = min(G - 1, max(0, (int)floorf((rx + HALF_NB) * INV_CELL)));
                int gy = min(G - 1, max(0, (int)floorf((ry + HALF_NB) * INV_CELL)));
                int slot = atomicAdd(cnt, 1);
                list[slot] = (j << 8) | (gy * G + gx);
            }
        }
        __syncthreads();

        // pooling: 16-way entry parallel, 4 dims/thread, 2-deep prefetch
        const int n    = *cnt;
        const int dim4 = (tid & 31) * 4;
        const int eg   = tid >> 5;                    // 0..15
        int e  = eg;
        int p0 = (e < n) ? list[e] : -1;
        int p1 = (e + 16 < n) ? list[e + 16] : -1;
        float4 v0 = {};
        if (p0 >= 0) v0 = *(const float4*)&hs[(p0 >> 8) * H + dim4];
        while (p0 >= 0) {
            int p2 = (e + 32 < n) ? list[e + 32] : -1;
            float4 v1 = {};
            if (p1 >= 0) v1 = *(const float4*)&hs[(p1 >> 8) * H + dim4];
            unsigned* gph = &lgrid[(p0 & 255) * H + dim4];
            atomicMax(gph + 0, map_f2u(v0.x));
            atomicMax(gph + 1, map_f2u(v0.y));
            atomicMax(gph + 2, map_f2u(v0.z));
            atomicMax(gph + 3, map_f2u(v0.w));
            e += 16; p0 = p1; p1 = p2; v0 = v1;
        }
        __syncthreads();

        ushort* dst = grid + (size_t)i * K_TOT;       // PLAIN row-major bf16
        for (int c = tid; c < K_TOT / 8; c += 512) {
            uint4 a = ((const uint4*)lgrid)[2 * c];
            uint4 bq = ((const uint4*)lgrid)[2 * c + 1];
            ushort tmp[8];
            tmp[0] = f2bf(unmap_u2f(a.x));  tmp[1] = f2bf(unmap_u2f(a.y));
            tmp[2] = f2bf(unmap_u2f(a.z));  tmp[3] = f2bf(unmap_u2f(a.w));
            tmp[4] = f2bf(unmap_u2f(bq.x)); tmp[5] = f2bf(unmap_u2f(bq.y));
            tmp[6] = f2bf(unmap_u2f(bq.z)); tmp[7] = f2bf(unmap_u2f(bq.w));
            *(bf16x8*)&dst[8 * c] = *(const bf16x8*)tmp;
        }
    } else if (blockIdx.x < N_PED + 128) {
        float* tile = (float*)smem;                   // [64][129] = 33024 B
        const int bw  = blockIdx.x - N_PED;
        const int k0w = bw * 64;

        for (int x = tid; x < 64 * H; x += 512) {
            int r = x >> 7, c = x & 127;
            tile[r * 129 + c] = W[(size_t)(k0w + r) * H + c];
        }
        __syncthreads();

        const int col = tid >> 2;                     // 0..127
        const int kh  = (tid & 3) * 16;
        ushort tmp[16];
        #pragma unroll
        for (int t = 0; t < 16; ++t) tmp[t] = f2bf(tile[(kh + t) * 129 + col]);
        ushort* w0 = Wt + (size_t)col * K_TOT + k0w + kh;
        *(bf16x8*)w0       = *(const bf16x8*)&tmp[0];
        *(bf16x8*)(w0 + 8) = *(const bf16x8*)&tmp[8];
    } else {
        const float4* b4 = (const float4*)b;
        float4* out4 = (float4*)out;
        const int b0 = (blockIdx.x - N_PED - 128) * 16384;
        for (int i2 = tid; i2 < 16384; i2 += 512) {
            int g = b0 + i2;
            out4[g] = b4[g & 31];
        }
    }
}

// A[1024][8192] bf16 @ Wt[128][8192] bf16 -> atomicAdd into bias-seeded out.
// No LDS, no barriers: B has zero intra-block reuse (cols partitioned per
// wave) and A's x4 wave reuse is L1-covered; grid+Wt are L2/L3-resident.
__global__ __launch_bounds__(256) void gemm_direct(const ushort* __restrict__ A,
                                                   const ushort* __restrict__ Wt,
                                                   float* __restrict__ out) {
    const int m0   = blockIdx.x * 32;
    const int k0   = blockIdx.y * KC;
    const int tid  = threadIdx.x;
    const int wave = tid >> 6, lane = tid & 63;
    const int ll   = lane & 15, lh = lane >> 4;

    // lane fragment bases: A row = m0 + mt*16 + ll, k = k0 + ks*32 + lh*8
    //                      B col = wave*32 + nt*16 + ll, same k
    const ushort* Ab = A  + (size_t)(m0 + ll) * K_TOT        + k0 + lh * 8;
    const ushort* Bb = Wt + (size_t)(wave * 32 + ll) * K_TOT + k0 + lh * 8;

    f32x4 acc[2][2] = {};   // [mt][nt]

    #pragma unroll 4
    for (int ks = 0; ks < KC / 32; ++ks) {
        const int kk = ks * 32;
        bf16x8 a0 = *(const bf16x8*)(Ab + kk);
        bf16x8 a1 = *(const bf16x8*)(Ab + (size_t)16 * K_TOT + kk);
        bf16x8 b0 = *(const bf16x8*)(Bb + kk);
        bf16x8 b1 = *(const bf16x8*)(Bb + (size_t)16 * K_TOT + kk);
        acc[0][0] = __builtin_amdgcn_mfma_f32_16x16x32_bf16(a0, b0, acc[0][0], 0, 0, 0);
        acc[0][1] = __builtin_amdgcn_mfma_f32_16x16x32_bf16(a0, b1, acc[0][1], 0, 0, 0);
        acc[1][0] = __builtin_amdgcn_mfma_f32_16x16x32_bf16(a1, b0, acc[1][0], 0, 0, 0);
        acc[1][1] = __builtin_amdgcn_mfma_f32_16x16x32_bf16(a1, b1, acc[1][1], 0, 0, 0);
    }

    // D layout: col = lane&15, row = (lane>>4)*4 + reg   [m89/m91]
    #pragma unroll
    for (int mt = 0; mt < 2; ++mt)
        #pragma unroll
        for (int nt = 0; nt < 2; ++nt) {
            int col = wave * 32 + nt * 16 + ll;
            int row = m0 + mt * 16 + lh * 4;
            #pragma unroll
            for (int r = 0; r < 4; ++r)
                atomicAdd(&out[(size_t)(row + r) * H + col], acc[mt][nt][r]);
        }
}

extern "C" void kernel_launch(void* const* d_in, const int* in_sizes, int n_in,
                              void* d_out, int out_size, void* d_ws, size_t ws_size,
                              hipStream_t stream) {
    const float* hs  = (const float*)d_in[0];   // [1024][128]
    const float* pos = (const float*)d_in[1];   // [1024][2]
    const float* Wm  = (const float*)d_in[2];   // [8192][128]
    const float* b   = (const float*)d_in[3];   // [128]
    float* out = (float*)d_out;                 // [1024][128]

    ushort* grid = (ushort*)d_ws;                               // 16 MB
    ushort* Wt   = (ushort*)((char*)d_ws + (16u << 20));        // 2 MB

    fused_pre<<<N_PED + 128 + 2, 512, 0, stream>>>(hs, pos, Wm, b, grid, Wt, out);
    gemm_direct<<<dim3(N_PED / 32, KSPLIT), 256, 0, stream>>>(grid, Wt, out);
}